// Round 16
// baseline (50.198 us; speedup 1.0000x reference)
//
#include <hip/hip_runtime.h>
#include <math.h>

#define NT 4096
#define MODES 64
#define ROWS 2048       // B*Ci == B*Co
#define TWO_PI 6.283185307179586f

typedef __attribute__((ext_vector_type(8))) short bf16x8;   // 8 bf16 (4 VGPRs)
typedef __attribute__((ext_vector_type(4))) float f32x4;    // MFMA acc

static __device__ __forceinline__ unsigned short bf16rn(float x) {
  unsigned u = __float_as_uint(x);
  u += 0x7FFFu + ((u >> 16) & 1u);   // round-to-nearest-even
  return (unsigned short)(u >> 16);
}

// ---------------------------------------------------------------------------
// K0: generate both basis tables (one dispatch, 512 blocks).
//  blocks 0..255:  Bg[n][t] (bf16): n<64 cos(2pi n t/4096)/4096, n>=64 -sin/4096
//  blocks 256..511: Cg[t][k2] (bf16): k2<64 cos(2pi k2 t/4096)*(-1)^t,
//                   k2>=64 -sin(2pi (k2-64) t/4096)*(-1)^t   (ICFT basis)
// ---------------------------------------------------------------------------
__global__ __launch_bounds__(256) void bgen_kernel(unsigned short* __restrict__ Bg,
                                                   unsigned short* __restrict__ Cg) {
  const int bx = (int)blockIdx.x;
  if (bx < 256) {
    const int e0 = (bx * 256 + (int)threadIdx.x) * 8;
    const int n = e0 >> 12;
    const int t0 = e0 & 4095;
    const int k = (n < 64) ? n : (n - 64);
    bf16x8 pack;
#pragma unroll
    for (int j = 0; j < 8; ++j) {
      const int ph = (k * (t0 + j)) & (NT - 1);
      float s, c;
      sincosf(TWO_PI * (float)ph / (float)NT, &s, &c);
      const float v = ((n < 64) ? c : -s) * (1.0f / (float)NT);
      pack[j] = (short)bf16rn(v);
    }
    *(bf16x8*)(Bg + e0) = pack;
  } else {
    const int e0 = ((bx - 256) * 256 + (int)threadIdx.x) * 8;
    const int t = e0 >> 7;
    const int k2b = e0 & 127;
    const float sgn = (t & 1) ? -1.f : 1.f;
    bf16x8 pack;
#pragma unroll
    for (int j = 0; j < 8; ++j) {
      const int k2 = k2b + j;
      const int k = (k2 < 64) ? k2 : (k2 - 64);
      const int ph = (k * t) & (NT - 1);
      float s, c;
      sincosf(TWO_PI * (float)ph / (float)NT, &s, &c);
      const float v = ((k2 < 64) ? c : -s) * sgn;
      pack[j] = (short)bf16rn(v);
    }
    *(bf16x8*)(Cg + e0) = pack;
  }
}

// ---------------------------------------------------------------------------
// K1: MFMA CFT partials + fused w-transpose.
//  B-operand fragments load DIRECTLY from Bg (L2-resident; zero intra-block
//  reuse across waves). A (shared by all 4 waves) stays LDS-staged with the
//  hi/lo bf16 split. S=16 restores 4.5 blocks/CU (round-15 lesson: S=8's
//  2.5 blocks/CU + imbalance was the regression, not the direct loads).
// ---------------------------------------------------------------------------
__global__ __launch_bounds__(256) void cft_mfma_kernel(
    const float* __restrict__ x, const unsigned short* __restrict__ Bg,
    float* __restrict__ xfp,
    const float* __restrict__ w_real, const float* __restrict__ w_imag,
    float* __restrict__ wrt, float* __restrict__ wit, int S) {
  __shared__ __align__(16) char smem[16896];
  const int tid = threadIdx.x;
  const int nCft = 64 * S;

  if ((int)blockIdx.x >= nCft) {
    float (*tile)[65] = (float (*)[65])smem;
    const int bx = (int)blockIdx.x - nCft;
    const int sel = bx >> 6;
    const int io0 = (bx & 63) * 64;
    const float* __restrict__ src = sel ? w_imag : w_real;
    float* __restrict__ dst = sel ? wit : wrt;
#pragma unroll
    for (int j = 0; j < 4; ++j) {
      const int idx = tid + j * 256;
      const int r = idx >> 4;
      const int kq = idx & 15;
      float4 v = ((const float4*)src)[(size_t)(io0 + r) * 16 + kq];
      tile[r][4 * kq + 0] = v.x; tile[r][4 * kq + 1] = v.y;
      tile[r][4 * kq + 2] = v.z; tile[r][4 * kq + 3] = v.w;
    }
    __syncthreads();
#pragma unroll
    for (int j = 0; j < 16; ++j) {
      const int idx = tid + j * 256;
      const int k = idx >> 6;
      const int r = idx & 63;
      dst[(size_t)k * 4096 + io0 + r] = tile[r][k];
    }
    return;
  }

  unsigned short* Ah = (unsigned short*)smem;          // [32 rows][64 k] bf16
  unsigned short* Al = (unsigned short*)(smem + 4096);

  const int rowblk = (int)blockIdx.x / S;
  const int ts = (int)blockIdx.x % S;
  const int row0 = rowblk * 32;
  const int t0 = ts * (NT / S);
  const int subs = (NT / S) / 64;

  const int lane = tid & 63;
  const int w = tid >> 6;

  f32x4 acc[2][2];
#pragma unroll
  for (int mt = 0; mt < 2; ++mt)
#pragma unroll
    for (int nt = 0; nt < 2; ++nt) acc[mt][nt] = (f32x4){0.f, 0.f, 0.f, 0.f};

  const int aru = tid & 7;
  const int arow = tid >> 3;
  const int kg = lane >> 4;

  for (int sub = 0; sub < subs; ++sub) {
    const int tb = t0 + sub * 64;
    __syncthreads();
    {  // A stage: x -> bf16 hi/lo, XOR-swizzled LDS
      const float* xp = x + (size_t)(row0 + arow) * NT + tb + aru * 8;
      const float4 v0 = *(const float4*)xp;
      const float4 v1 = *(const float4*)(xp + 4);
      float xv[8] = {v0.x, v0.y, v0.z, v0.w, v1.x, v1.y, v1.z, v1.w};
      bf16x8 ph, pl;
#pragma unroll
      for (int j = 0; j < 8; ++j) {
        const unsigned short h = bf16rn(xv[j]);
        ph[j] = (short)h;
        const float hf = __uint_as_float((unsigned)h << 16);
        pl[j] = (short)bf16rn(xv[j] - hf);
      }
      const int col = (aru ^ (arow & 7)) * 8;
      *(bf16x8*)(Ah + arow * 64 + col) = ph;
      *(bf16x8*)(Al + arow * 64 + col) = pl;
    }
    __syncthreads();
#pragma unroll
    for (int ks = 0; ks < 2; ++ks) {
      bf16x8 bf[2];
#pragma unroll
      for (int nt = 0; nt < 2; ++nt) {   // direct global B-fragment (L2 hit)
        const int n = w * 32 + nt * 16 + (lane & 15);
        bf[nt] = *(const bf16x8*)(Bg + (size_t)n * NT + tb + (ks * 4 + kg) * 8);
      }
#pragma unroll
      for (int mt = 0; mt < 2; ++mt) {
        const int row = mt * 16 + (lane & 15);
        const int col = ((ks * 4 + kg) ^ (row & 7)) * 8;
        const bf16x8 ah = *(const bf16x8*)(Ah + row * 64 + col);
        const bf16x8 al = *(const bf16x8*)(Al + row * 64 + col);
#pragma unroll
        for (int nt = 0; nt < 2; ++nt) {
          acc[mt][nt] = __builtin_amdgcn_mfma_f32_16x16x32_bf16(ah, bf[nt], acc[mt][nt], 0, 0, 0);
          acc[mt][nt] = __builtin_amdgcn_mfma_f32_16x16x32_bf16(al, bf[nt], acc[mt][nt], 0, 0, 0);
        }
      }
    }
  }
  const int nb = w * 32 + (lane & 15);
#pragma unroll
  for (int nt = 0; nt < 2; ++nt) {
    const int n = nb + nt * 16;
    const int plane = n >> 6;
    const int kk = n & 63;
#pragma unroll
    for (int mt = 0; mt < 2; ++mt) {
      const int rl = mt * 16 + (lane >> 4) * 4;
      float4 st = {acc[mt][nt][0], acc[mt][nt][1], acc[mt][nt][2], acc[mt][nt][3]};
      ((float4*)xfp)[((((size_t)ts * 64 + rowblk) * 2 + plane) * 64 + kk) * 8 + (rl >> 2)] = st;
    }
  }
}

// ---------------------------------------------------------------------------
// K2: sum partials + spectral mix (round-12 verbatim, passing).
// ---------------------------------------------------------------------------
__global__ __launch_bounds__(256) void mix_kernel(
    const float* __restrict__ wrt, const float* __restrict__ wit,
    const float* __restrict__ xfp, float2* __restrict__ yf_t, int S) {
  __shared__ float2 wsc[4096];
  __shared__ float2 xsh[256];
  const int k = blockIdx.x & 63;
  const int bq = blockIdx.x >> 6;
  const int tid = threadIdx.x;
#pragma unroll
  for (int j = 0; j < 4; ++j) {
    const int idx = tid + 256 * j;
    float4 vr = ((const float4*)(wrt + (size_t)k * 4096))[idx];
    float4 vi = ((const float4*)(wit + (size_t)k * 4096))[idx];
    wsc[4 * idx + 0] = make_float2(vr.x, vi.x);
    wsc[4 * idx + 1] = make_float2(vr.y, vi.y);
    wsc[4 * idx + 2] = make_float2(vr.z, vi.z);
    wsc[4 * idx + 3] = make_float2(vr.w, vi.w);
  }
  {
    const int R = bq * 256 + tid;
    const int rowblk = R >> 5;
    const int rl = R & 31;
    float2 acc = make_float2(0.f, 0.f);
    for (int s = 0; s < S; ++s) {
      const size_t b0 = (((size_t)s * 64 + rowblk) * 2) * 2048;
      acc.x += xfp[b0 + (size_t)k * 32 + rl];
      acc.y += xfp[b0 + 2048 + (size_t)k * 32 + rl];
    }
    xsh[tid] = acc;
  }
  __syncthreads();
  const int o = tid & 63;
  const int bl = tid >> 6;
  float accr = 0.f, acci = 0.f;
#pragma unroll 8
  for (int i = 0; i < 64; ++i) {
    const float2 xv = xsh[bl * 64 + i];
    const float2 w = wsc[i * 64 + o];
    accr = fmaf(xv.x, w.x, accr); accr = fmaf(-xv.y, w.y, accr);
    acci = fmaf(xv.x, w.y, acci); acci = fmaf( xv.y, w.x, acci);
  }
  yf_t[(size_t)k * ROWS + bq * 256 + bl * 64 + o] = make_float2(accr, acci);
}

// ---------------------------------------------------------------------------
// K3: MFMA ICFT. Out[2048,4096] = Y2[2048,128] x C[128,4096].
//  C fragments load DIRECTLY from Cg (zero intra-block reuse; L2-resident) ->
//  the sub-loop is barrier-free. Ay staged once (cross-wave reuse), A-frags
//  hoisted to registers. LDS 8 KB.
// grid = 1024: 64 rowgroups x 16 t-groups.
// ---------------------------------------------------------------------------
__global__ __launch_bounds__(256) void icft_mfma_kernel(
    const float2* __restrict__ yf_t, const unsigned short* __restrict__ Cg,
    float* __restrict__ out) {
  __shared__ __align__(16) unsigned short Ay[32 * 128];  // 8 KB
  const int tid = threadIdx.x;
  const int rgrp = (int)blockIdx.x >> 4;
  const int tgrp = (int)blockIdx.x & 15;
  const int row0 = rgrp * 32;
  const int tb0 = tgrp * 256;
  const int lane = tid & 63;
  const int w = tid >> 6;

  // ---- Y stage: yf_t[k][row0..row0+32) -> Ay[row][k2] bf16, unit-swizzled ----
#pragma unroll
  for (int it = 0; it < 8; ++it) {
    const int idx = tid + it * 256;
    const int k = idx >> 5;          // 0..63
    const int rl = idx & 31;
    const float2 y = yf_t[(size_t)k * ROWS + row0 + rl];
    const int ur = (k >> 3) ^ (rl & 7);          // re unit 0..7
    Ay[rl * 128 + ur * 8 + (k & 7)] = bf16rn(y.x);
    Ay[rl * 128 + (8 | ur) * 8 + (k & 7)] = bf16rn(y.y);  // im unit 8..15
  }
  __syncthreads();

  // ---- A-fragments to registers ----
  bf16x8 afr[2][4];
#pragma unroll
  for (int mt = 0; mt < 2; ++mt) {
    const int row = mt * 16 + (lane & 15);
#pragma unroll
    for (int ks = 0; ks < 4; ++ks) {
      const int unit = ks * 4 + (lane >> 4);
      const int cu = unit ^ (row & 7);
      afr[mt][ks] = *(const bf16x8*)(Ay + row * 128 + cu * 8);
    }
  }

  const int tl = w * 16 + (lane & 15);
  for (int sub = 0; sub < 4; ++sub) {
    const int t = tb0 + sub * 64 + tl;
    f32x4 acc[2];
    acc[0] = (f32x4){0.f, 0.f, 0.f, 0.f};
    acc[1] = (f32x4){0.f, 0.f, 0.f, 0.f};
#pragma unroll
    for (int ks = 0; ks < 4; ++ks) {
      const int unit = ks * 4 + (lane >> 4);
      const bf16x8 bf = *(const bf16x8*)(Cg + (size_t)t * 128 + unit * 8);
      acc[0] = __builtin_amdgcn_mfma_f32_16x16x32_bf16(afr[0][ks], bf, acc[0], 0, 0, 0);
      acc[1] = __builtin_amdgcn_mfma_f32_16x16x32_bf16(afr[1][ks], bf, acc[1], 0, 0, 0);
    }
#pragma unroll
    for (int mt = 0; mt < 2; ++mt) {
      const int rbase = row0 + mt * 16 + (lane >> 4) * 4;
#pragma unroll
      for (int reg = 0; reg < 4; ++reg) {
        out[(size_t)(rbase + reg) * NT + t] = acc[mt][reg];
      }
    }
  }
}

extern "C" void kernel_launch(void* const* d_in, const int* in_sizes, int n_in,
                              void* d_out, int out_size, void* d_ws, size_t ws_size,
                              hipStream_t stream) {
  const float* x      = (const float*)d_in[0];
  const float* w_real = (const float*)d_in[1];
  const float* w_imag = (const float*)d_in[2];
  float* out = (float*)d_out;

  const size_t MB = (size_t)ROWS * MODES * sizeof(float2);  // 1 MiB units
  int S = 16;
  while (S > 4 && (size_t)(S + 6) * MB > ws_size) S >>= 1;

  char* wsp = (char*)d_ws;
  float*  xfp  = (float*)wsp;                         // S MB
  float2* yf_t = (float2*)(wsp + (size_t)S * MB);     // 2 MB: [k][row]
  float*  wrt  = (float*)(wsp + (size_t)(S + 2) * MB);
  float*  wit  = (float*)(wsp + (size_t)(S + 3) * MB);
  unsigned short* Bg = (unsigned short*)(wsp + (size_t)(S + 4) * MB);  // 1 MB
  unsigned short* Cg = (unsigned short*)(wsp + (size_t)(S + 5) * MB);  // 1 MB

  bgen_kernel<<<512, 256, 0, stream>>>(Bg, Cg);
  cft_mfma_kernel<<<64 * S + 128, 256, 0, stream>>>(x, Bg, xfp, w_real, w_imag,
                                                    wrt, wit, S);
  mix_kernel<<<512, 256, 0, stream>>>(wrt, wit, xfp, yf_t, S);
  icft_mfma_kernel<<<1024, 256, 0, stream>>>(yf_t, Cg, out);
}

// Round 20
// 42.767 us; speedup vs baseline: 1.1737x; 1.1737x over previous
//
#include <hip/hip_runtime.h>
#include <math.h>

#define NT 4096
#define MODES 64
#define ROWS 2048       // B*Ci == B*Co
#define TWO_PI 6.283185307179586f

typedef __attribute__((ext_vector_type(8))) short bf16x8;   // 8 bf16 (4 VGPRs)
typedef __attribute__((ext_vector_type(4))) float f32x4;    // MFMA acc

static __device__ __forceinline__ unsigned short bf16rn(float x) {
  unsigned u = __float_as_uint(x);
  u += 0x7FFFu + ((u >> 16) & 1u);   // round-to-nearest-even
  return (unsigned short)(u >> 16);
}

// ---------------------------------------------------------------------------
// K0: generate both basis tables (one dispatch, 512 blocks).
//  blocks 0..255:  Bg[n][t] (bf16): n<64 cos(2pi n t/4096)/4096, n>=64 -sin/4096
//  blocks 256..511: Cg[t][k2] (bf16): k2<64 cos(2pi k2 t/4096)*(-1)^t,
//                   k2>=64 -sin(2pi (k2-64) t/4096)*(-1)^t   (ICFT basis)
// ---------------------------------------------------------------------------
__global__ __launch_bounds__(256) void bgen_kernel(unsigned short* __restrict__ Bg,
                                                   unsigned short* __restrict__ Cg) {
  const int bx = (int)blockIdx.x;
  if (bx < 256) {
    const int e0 = (bx * 256 + (int)threadIdx.x) * 8;
    const int n = e0 >> 12;
    const int t0 = e0 & 4095;
    const int k = (n < 64) ? n : (n - 64);
    bf16x8 pack;
#pragma unroll
    for (int j = 0; j < 8; ++j) {
      const int ph = (k * (t0 + j)) & (NT - 1);
      float s, c;
      sincosf(TWO_PI * (float)ph / (float)NT, &s, &c);
      const float v = ((n < 64) ? c : -s) * (1.0f / (float)NT);
      pack[j] = (short)bf16rn(v);
    }
    *(bf16x8*)(Bg + e0) = pack;
  } else {
    const int e0 = ((bx - 256) * 256 + (int)threadIdx.x) * 8;
    const int t = e0 >> 7;
    const int k2b = e0 & 127;
    const float sgn = (t & 1) ? -1.f : 1.f;
    bf16x8 pack;
#pragma unroll
    for (int j = 0; j < 8; ++j) {
      const int k2 = k2b + j;
      const int k = (k2 < 64) ? k2 : (k2 - 64);
      const int ph = (k * t) & (NT - 1);
      float s, c;
      sincosf(TWO_PI * (float)ph / (float)NT, &s, &c);
      const float v = ((k2 < 64) ? c : -s) * sgn;
      pack[j] = (short)bf16rn(v);
    }
    *(bf16x8*)(Cg + e0) = pack;
  }
}

// ---------------------------------------------------------------------------
// K1: MFMA CFT partials + fused w-transpose (round-13 verified, 42.7 us).
//  blocks [0, 64*S): M-tile (32 rows) x K-chunk ts (4096/S t) ->
//     xfp[ts][rowblk][plane(re/im)][k][rl] (fp32)
//  blocks [64*S, +128): w transpose -> w_t[k][i*64+o]
//  GEMM: D[32,128] += (Xh + Xl)[32,64] x B[64,128] per 64-t sub-step,
//  v_mfma_f32_16x16x32_bf16, 4 waves x (2 m-tiles x 2 n-tiles).
//  LDS XOR swizzle (col16 ^= row&7) on A and B -> 2-way (free) frag reads.
// ---------------------------------------------------------------------------
__global__ __launch_bounds__(256) void cft_mfma_kernel(
    const float* __restrict__ x, const unsigned short* __restrict__ Bg,
    float* __restrict__ xfp,
    const float* __restrict__ w_real, const float* __restrict__ w_imag,
    float* __restrict__ wrt, float* __restrict__ wit, int S) {
  __shared__ __align__(16) char smem[24576];
  const int tid = threadIdx.x;
  const int nCft = 64 * S;

  if ((int)blockIdx.x >= nCft) {
    float (*tile)[65] = (float (*)[65])smem;
    const int bx = (int)blockIdx.x - nCft;
    const int sel = bx >> 6;
    const int io0 = (bx & 63) * 64;
    const float* __restrict__ src = sel ? w_imag : w_real;
    float* __restrict__ dst = sel ? wit : wrt;
#pragma unroll
    for (int j = 0; j < 4; ++j) {
      const int idx = tid + j * 256;
      const int r = idx >> 4;
      const int kq = idx & 15;
      float4 v = ((const float4*)src)[(size_t)(io0 + r) * 16 + kq];
      tile[r][4 * kq + 0] = v.x; tile[r][4 * kq + 1] = v.y;
      tile[r][4 * kq + 2] = v.z; tile[r][4 * kq + 3] = v.w;
    }
    __syncthreads();
#pragma unroll
    for (int j = 0; j < 16; ++j) {
      const int idx = tid + j * 256;
      const int k = idx >> 6;
      const int r = idx & 63;
      dst[(size_t)k * 4096 + io0 + r] = tile[r][k];
    }
    return;
  }

  unsigned short* Ah = (unsigned short*)smem;
  unsigned short* Al = (unsigned short*)(smem + 4096);
  unsigned short* Bs = (unsigned short*)(smem + 8192);

  const int rowblk = (int)blockIdx.x / S;
  const int ts = (int)blockIdx.x % S;
  const int row0 = rowblk * 32;
  const int t0 = ts * (NT / S);
  const int subs = (NT / S) / 64;

  const int lane = tid & 63;
  const int w = tid >> 6;

  f32x4 acc[2][2];
#pragma unroll
  for (int mt = 0; mt < 2; ++mt)
#pragma unroll
    for (int nt = 0; nt < 2; ++nt) acc[mt][nt] = (f32x4){0.f, 0.f, 0.f, 0.f};

  const int aru = tid & 7;
  const int arow = tid >> 3;

  for (int sub = 0; sub < subs; ++sub) {
    const int tb = t0 + sub * 64;
    __syncthreads();
    {
      const float* xp = x + (size_t)(row0 + arow) * NT + tb + aru * 8;
      const float4 v0 = *(const float4*)xp;
      const float4 v1 = *(const float4*)(xp + 4);
      float xv[8] = {v0.x, v0.y, v0.z, v0.w, v1.x, v1.y, v1.z, v1.w};
      bf16x8 ph, pl;
#pragma unroll
      for (int j = 0; j < 8; ++j) {
        const unsigned short h = bf16rn(xv[j]);
        ph[j] = (short)h;
        const float hf = __uint_as_float((unsigned)h << 16);
        pl[j] = (short)bf16rn(xv[j] - hf);
      }
      const int col = (aru ^ (arow & 7)) * 8;
      *(bf16x8*)(Ah + arow * 64 + col) = ph;
      *(bf16x8*)(Al + arow * 64 + col) = pl;
    }
#pragma unroll
    for (int it = 0; it < 4; ++it) {
      const int idx = tid + it * 256;
      const int ku = idx & 7;
      const int n = idx >> 3;
      const bf16x8 v = *(const bf16x8*)(Bg + (size_t)n * NT + tb + ku * 8);
      const int col = (ku ^ (n & 7)) * 8;
      *(bf16x8*)(Bs + n * 64 + col) = v;
    }
    __syncthreads();
    const int kg = lane >> 4;
#pragma unroll
    for (int ks = 0; ks < 2; ++ks) {
      bf16x8 bf[2];
#pragma unroll
      for (int nt = 0; nt < 2; ++nt) {
        const int n = w * 32 + nt * 16 + (lane & 15);
        const int col = ((ks * 4 + kg) ^ (n & 7)) * 8;
        bf[nt] = *(const bf16x8*)(Bs + n * 64 + col);
      }
#pragma unroll
      for (int mt = 0; mt < 2; ++mt) {
        const int row = mt * 16 + (lane & 15);
        const int col = ((ks * 4 + kg) ^ (row & 7)) * 8;
        const bf16x8 ah = *(const bf16x8*)(Ah + row * 64 + col);
        const bf16x8 al = *(const bf16x8*)(Al + row * 64 + col);
#pragma unroll
        for (int nt = 0; nt < 2; ++nt) {
          acc[mt][nt] = __builtin_amdgcn_mfma_f32_16x16x32_bf16(ah, bf[nt], acc[mt][nt], 0, 0, 0);
          acc[mt][nt] = __builtin_amdgcn_mfma_f32_16x16x32_bf16(al, bf[nt], acc[mt][nt], 0, 0, 0);
        }
      }
    }
  }
  const int nb = w * 32 + (lane & 15);
#pragma unroll
  for (int nt = 0; nt < 2; ++nt) {
    const int n = nb + nt * 16;
    const int plane = n >> 6;
    const int kk = n & 63;
#pragma unroll
    for (int mt = 0; mt < 2; ++mt) {
      const int rl = mt * 16 + (lane >> 4) * 4;
      float4 st = {acc[mt][nt][0], acc[mt][nt][1], acc[mt][nt][2], acc[mt][nt][3]};
      ((float4*)xfp)[((((size_t)ts * 64 + rowblk) * 2 + plane) * 64 + kk) * 8 + (rl >> 2)] = st;
    }
  }
}

// ---------------------------------------------------------------------------
// K2: sum the S partials (coalesced, two planes) + spectral mix from LDS.
//   yf[b,o,k] = sum_i xf[b,i,k] * W[i,o,k]
// grid = 512: k = bx&63, bq = bx>>6 (4 b's = 256 rows each).
// ---------------------------------------------------------------------------
__global__ __launch_bounds__(256) void mix_kernel(
    const float* __restrict__ wrt, const float* __restrict__ wit,
    const float* __restrict__ xfp, float2* __restrict__ yf_t, int S) {
  __shared__ float2 wsc[4096];
  __shared__ float2 xsh[256];
  const int k = blockIdx.x & 63;
  const int bq = blockIdx.x >> 6;
  const int tid = threadIdx.x;
#pragma unroll
  for (int j = 0; j < 4; ++j) {
    const int idx = tid + 256 * j;
    float4 vr = ((const float4*)(wrt + (size_t)k * 4096))[idx];
    float4 vi = ((const float4*)(wit + (size_t)k * 4096))[idx];
    wsc[4 * idx + 0] = make_float2(vr.x, vi.x);
    wsc[4 * idx + 1] = make_float2(vr.y, vi.y);
    wsc[4 * idx + 2] = make_float2(vr.z, vi.z);
    wsc[4 * idx + 3] = make_float2(vr.w, vi.w);
  }
  {
    const int R = bq * 256 + tid;
    const int rowblk = R >> 5;
    const int rl = R & 31;
    float2 acc = make_float2(0.f, 0.f);
    for (int s = 0; s < S; ++s) {
      const size_t b0 = (((size_t)s * 64 + rowblk) * 2) * 2048;
      acc.x += xfp[b0 + (size_t)k * 32 + rl];
      acc.y += xfp[b0 + 2048 + (size_t)k * 32 + rl];
    }
    xsh[tid] = acc;
  }
  __syncthreads();
  const int o = tid & 63;
  const int bl = tid >> 6;
  float accr = 0.f, acci = 0.f;
#pragma unroll 8
  for (int i = 0; i < 64; ++i) {
    const float2 xv = xsh[bl * 64 + i];
    const float2 w = wsc[i * 64 + o];
    accr = fmaf(xv.x, w.x, accr); accr = fmaf(-xv.y, w.y, accr);
    acci = fmaf(xv.x, w.y, acci); acci = fmaf( xv.y, w.x, acci);
  }
  yf_t[(size_t)k * ROWS + bq * 256 + bl * 64 + o] = make_float2(accr, acci);
}

// ---------------------------------------------------------------------------
// K3: MFMA ICFT (round-13 verified). Out[2048,4096] = Y2[2048,128] x C[128,4096].
// Block: 32 rows x 256 t, 4 waves. Y2 staged once (swizzled bf16 LDS, then
// A-frags in registers); C staged per 64-t sub (16 KB); wave w owns t-tile w.
// grid = 1024: 64 rowgroups x 16 t-groups.
// ---------------------------------------------------------------------------
__global__ __launch_bounds__(256) void icft_mfma_kernel(
    const float2* __restrict__ yf_t, const unsigned short* __restrict__ Cg,
    float* __restrict__ out) {
  __shared__ __align__(16) char smem[24576];
  unsigned short* Ay = (unsigned short*)smem;          // [32 rows][128 k2], 8 KB
  unsigned short* Cs = (unsigned short*)(smem + 8192); // [64 t][128 k2], 16 KB
  const int tid = threadIdx.x;
  const int rgrp = (int)blockIdx.x >> 4;
  const int tgrp = (int)blockIdx.x & 15;
  const int row0 = rgrp * 32;
  const int tb0 = tgrp * 256;
  const int lane = tid & 63;
  const int w = tid >> 6;

  // ---- Y stage: yf_t[k][row0..row0+32) -> Ay[row][k2] bf16, unit-swizzled ----
#pragma unroll
  for (int it = 0; it < 8; ++it) {
    const int idx = tid + it * 256;
    const int k = idx >> 5;          // 0..63
    const int rl = idx & 31;
    const float2 y = yf_t[(size_t)k * ROWS + row0 + rl];
    const int ur = (k >> 3) ^ (rl & 7);          // re unit 0..7
    Ay[rl * 128 + ur * 8 + (k & 7)] = bf16rn(y.x);
    Ay[rl * 128 + (8 | ur) * 8 + (k & 7)] = bf16rn(y.y);  // im unit 8..15
  }
  __syncthreads();

  // ---- A-fragments to registers: frag[mt][ks], row = mt*16+(lane&15) ----
  bf16x8 afr[2][4];
#pragma unroll
  for (int mt = 0; mt < 2; ++mt) {
    const int row = mt * 16 + (lane & 15);
#pragma unroll
    for (int ks = 0; ks < 4; ++ks) {
      const int unit = ks * 4 + (lane >> 4);
      const int cu = unit ^ (row & 7);
      afr[mt][ks] = *(const bf16x8*)(Ay + row * 128 + cu * 8);
    }
  }

  for (int sub = 0; sub < 4; ++sub) {
    const int tb = tb0 + sub * 64;
    __syncthreads();
    // C stage: Cg[t][k2] rows tb..tb+64 -> Cs[tl][128], unit-swizzled
#pragma unroll
    for (int it = 0; it < 4; ++it) {
      const int idx = tid + it * 256;   // 0..1023
      const int ku = idx & 15;
      const int tl = idx >> 4;          // 0..63
      const bf16x8 v = *(const bf16x8*)(Cg + (size_t)(tb + tl) * 128 + ku * 8);
      Cs[tl * 128 + (ku ^ (tl & 7)) * 8] = 0;  // placeholder overwritten below
      *(bf16x8*)(Cs + tl * 128 + (ku ^ (tl & 7)) * 8) = v;
    }
    __syncthreads();
    // wave w owns t-tile [tb + w*16, +16)
    const int tl = w * 16 + (lane & 15);
    f32x4 acc[2];
    acc[0] = (f32x4){0.f, 0.f, 0.f, 0.f};
    acc[1] = (f32x4){0.f, 0.f, 0.f, 0.f};
#pragma unroll
    for (int ks = 0; ks < 4; ++ks) {
      const int unit = ks * 4 + (lane >> 4);
      const int cu = unit ^ (tl & 7);
      const bf16x8 bf = *(const bf16x8*)(Cs + tl * 128 + cu * 8);
      acc[0] = __builtin_amdgcn_mfma_f32_16x16x32_bf16(afr[0][ks], bf, acc[0], 0, 0, 0);
      acc[1] = __builtin_amdgcn_mfma_f32_16x16x32_bf16(afr[1][ks], bf, acc[1], 0, 0, 0);
    }
    const int t = tb + tl;
#pragma unroll
    for (int mt = 0; mt < 2; ++mt) {
      const int rbase = row0 + mt * 16 + (lane >> 4) * 4;
#pragma unroll
      for (int reg = 0; reg < 4; ++reg) {
        out[(size_t)(rbase + reg) * NT + t] = acc[mt][reg];
      }
    }
  }
}

extern "C" void kernel_launch(void* const* d_in, const int* in_sizes, int n_in,
                              void* d_out, int out_size, void* d_ws, size_t ws_size,
                              hipStream_t stream) {
  const float* x      = (const float*)d_in[0];
  const float* w_real = (const float*)d_in[1];
  const float* w_imag = (const float*)d_in[2];
  float* out = (float*)d_out;

  const size_t MB = (size_t)ROWS * MODES * sizeof(float2);  // 1 MiB units
  int S = 16;
  while (S > 4 && (size_t)(S + 6) * MB > ws_size) S >>= 1;

  char* wsp = (char*)d_ws;
  float*  xfp  = (float*)wsp;                         // S MB
  float2* yf_t = (float2*)(wsp + (size_t)S * MB);     // 2 MB: [k][row]
  float*  wrt  = (float*)(wsp + (size_t)(S + 2) * MB);
  float*  wit  = (float*)(wsp + (size_t)(S + 3) * MB);
  unsigned short* Bg = (unsigned short*)(wsp + (size_t)(S + 4) * MB);  // 1 MB
  unsigned short* Cg = (unsigned short*)(wsp + (size_t)(S + 5) * MB);  // 1 MB

  bgen_kernel<<<512, 256, 0, stream>>>(Bg, Cg);
  cft_mfma_kernel<<<64 * S + 128, 256, 0, stream>>>(x, Bg, xfp, w_real, w_imag,
                                                    wrt, wit, S);
  mix_kernel<<<512, 256, 0, stream>>>(wrt, wit, xfp, yf_t, S);
  icft_mfma_kernel<<<1024, 256, 0, stream>>>(yf_t, Cg, out);
}